// Round 14
// baseline (521.479 us; speedup 1.0000x reference)
//
#include <hip/hip_runtime.h>
#include <math.h>

#define Bsz 64
#define Nn 1024
#define Dd 768
#define TOPK 8

// ---------------------------------------------------------------------------
// Unfused IEEE f32 primitives (reference FFT = ducc/pocketfft C++ compiled
// for baseline x86-64: separate mul/add roundings, no FMA contraction).
// ---------------------------------------------------------------------------
__device__ __forceinline__ float fadd(float a, float b) {
#pragma clang fp contract(off)
    return a + b; }
__device__ __forceinline__ float fsub(float a, float b) {
#pragma clang fp contract(off)
    return a - b; }
__device__ __forceinline__ float fmul(float a, float b) {
#pragma clang fp contract(off)
    return a * b; }

struct c64 { float r, i; };
__device__ __forceinline__ c64 cadd(c64 a, c64 b) { return {fadd(a.r,b.r), fadd(a.i,b.i)}; }
__device__ __forceinline__ c64 csub(c64 a, c64 b) { return {fsub(a.r,b.r), fsub(a.i,b.i)}; }

#define HSQT2 0.70710678118654752440f
template<bool FWD> __device__ __forceinline__ c64 rot90(c64 a) {
    return FWD ? c64{a.i, -a.r} : c64{-a.i, a.r}; }
template<bool FWD> __device__ __forceinline__ c64 rotx45(c64 a) {
    if (FWD) return { fmul(HSQT2, fadd(a.r, a.i)), fmul(HSQT2, fsub(a.i, a.r)) };
    else     return { fmul(HSQT2, fsub(a.r, a.i)), fmul(HSQT2, fadd(a.i, a.r)) }; }
template<bool FWD> __device__ __forceinline__ c64 rotx135(c64 a) {
    if (FWD) return { fmul(HSQT2, fsub(a.i, a.r)), fmul(-HSQT2, fadd(a.r, a.i)) };
    else     return { fmul(-HSQT2, fadd(a.r, a.i)), fmul(HSQT2, fsub(a.r, a.i)) }; }
template<bool FWD> __device__ __forceinline__ c64 cmulw(c64 a, c64 w) {
    if (FWD) return { fadd(fmul(a.r,w.r), fmul(a.i,w.i)), fsub(fmul(a.i,w.r), fmul(a.r,w.i)) };
    else     return { fsub(fmul(a.r,w.r), fmul(a.i,w.i)), fadd(fmul(a.r,w.i), fmul(a.i,w.r)) }; }

// ---------------------------------------------------------------------------
// pocketfft/ducc cfftp passes for n=768, factors [8,8,4,3].
// ---------------------------------------------------------------------------
template<bool FWD, int IDO, int L1>
__device__ void pass8x(int lane, const c64* __restrict__ in, c64* __restrict__ out,
                       const c64* __restrict__ T) {
    for (int u = lane; u < 96; u += 64) {
        const int k = u / IDO, i = u - k * IDO;
        const int ib = i + IDO * 8 * k;
        c64 c0 = in[ib],       c1 = in[ib+IDO],   c2 = in[ib+2*IDO], c3 = in[ib+3*IDO];
        c64 c4 = in[ib+4*IDO], c5 = in[ib+5*IDO], c6 = in[ib+6*IDO], c7 = in[ib+7*IDO];
        c64 a1 = cadd(c1,c5), a5 = csub(c1,c5), a3 = cadd(c3,c7), a7 = csub(c3,c7), t;
        t = a1; a1 = cadd(a1,a3); a3 = csub(t,a3);
        a3 = rot90<FWD>(a3);
        a7 = rot90<FWD>(a7);
        t = a5; a5 = cadd(a5,a7); a7 = csub(t,a7);
        a5 = rotx45<FWD>(a5); a7 = rotx135<FWD>(a7);
        c64 a0 = cadd(c0,c4), a4 = csub(c0,c4), a2 = cadd(c2,c6), a6 = csub(c2,c6);
        a6 = rot90<FWD>(a6);
        t = a0; a0 = cadd(a0,a2); a2 = csub(t,a2);
        t = a4; a4 = cadd(a4,a6); a6 = csub(t,a6);
        c64 o0 = cadd(a0,a1), o4 = csub(a0,a1);
        c64 o1 = cadd(a4,a5), o5 = csub(a4,a5);
        c64 o2 = cadd(a2,a3), o6 = csub(a2,a3);
        c64 o3 = cadd(a6,a7), o7 = csub(a6,a7);
        if (i) {
            o1 = cmulw<FWD>(o1, T[L1*i]);   o2 = cmulw<FWD>(o2, T[2*L1*i]);
            o3 = cmulw<FWD>(o3, T[3*L1*i]); o4 = cmulw<FWD>(o4, T[4*L1*i]);
            o5 = cmulw<FWD>(o5, T[5*L1*i]); o6 = cmulw<FWD>(o6, T[6*L1*i]);
            o7 = cmulw<FWD>(o7, T[7*L1*i]);
        }
        const int ob = i + IDO * k;
        out[ob]          = o0; out[ob+IDO*L1]   = o1; out[ob+2*IDO*L1] = o2;
        out[ob+3*IDO*L1] = o3; out[ob+4*IDO*L1] = o4; out[ob+5*IDO*L1] = o5;
        out[ob+6*IDO*L1] = o6; out[ob+7*IDO*L1] = o7;
    }
}

template<bool FWD>   // ido=3, l1=64
__device__ void pass4x(int lane, const c64* __restrict__ in, c64* __restrict__ out,
                       const c64* __restrict__ T) {
    for (int u = lane; u < 192; u += 64) {
        const int k = u / 3, i = u - 3 * k;
        const int ib = i + 12 * k;
        c64 c0 = in[ib], c1 = in[ib+3], c2 = in[ib+6], c3 = in[ib+9];
        c64 t2 = cadd(c0,c2), t1 = csub(c0,c2), t3 = cadd(c1,c3), t4 = csub(c1,c3);
        t4 = rot90<FWD>(t4);
        c64 o0 = cadd(t2,t3), o2 = csub(t2,t3), o1 = cadd(t1,t4), o3 = csub(t1,t4);
        if (i) { o1 = cmulw<FWD>(o1, T[64*i]); o2 = cmulw<FWD>(o2, T[128*i]);
                 o3 = cmulw<FWD>(o3, T[192*i]); }
        const int ob = i + 3 * k;
        out[ob] = o0; out[ob+192] = o1; out[ob+384] = o2; out[ob+576] = o3;
    }
}

template<bool FWD>   // ido=1, l1=256
__device__ void pass3x(int lane, const c64* __restrict__ in, c64* __restrict__ out) {
#pragma clang fp contract(off)
    const float tw1r = -0.5f;
    const float tw1i = FWD ? -0.86602540378443864676f : 0.86602540378443864676f;
    for (int k = lane; k < 256; k += 64) {
        c64 c0 = in[3*k], c1 = in[3*k+1], c2 = in[3*k+2];
        c64 t1 = cadd(c1,c2), t2 = csub(c1,c2);
        c64 o0 = cadd(c0,t1);
        c64 t3 = { fadd(c0.r, fmul(tw1r, t1.r)), fadd(c0.i, fmul(tw1r, t1.i)) };
        c64 t4 = { fmul(-tw1i, t2.i), fmul(tw1i, t2.r) };
        c64 o1 = cadd(t3,t4), o2 = csub(t3,t4);
        out[k] = o0; out[k+256] = o1; out[k+512] = o2;
    }
}

// ---------------------------------------------------------------------------
// Tables: twiddles T[m]=f32(exp(2πi m/768)); multiplier via CORRECTLY-ROUNDED
// f32 exp (host libm expf on glibc>=2.27 is CR; jax/XLA lowers jnp.exp(f32)
// to libm expf) — the single change vs the R5/R8 c64 replica.
// ---------------------------------------------------------------------------
__global__ __launch_bounds__(1024) void build_tables(c64* __restrict__ Tg,
                                                     float* __restrict__ Pg) {
    __shared__ float mArr[768];
    const int tid = threadIdx.x;
    if (tid < 768) {
#pragma clang fp contract(off)
        float pos = (float)(tid - 383);
        float sig = (float)sqrt(768.0);
        float t1 = pos / sig;
        float sq = t1 * t1;
        float xin = -0.5f * sq;
        mArr[tid] = (float)exp((double)xin);     // CR f32 exp
        double a = (double)tid / 384.0;
        Tg[tid] = { (float)cospi(a), (float)sinpi(a) };
    }
    __syncthreads();
    if (tid < 768) Pg[tid] = mArr[(tid + 384) % 768];
}

__global__ void zero_votes(float* __restrict__ votes) {
    votes[blockIdx.x * 256 + threadIdx.x] = 0.0f;
}

// ---------------------------------------------------------------------------
// Kernel A: per-row pocketfft-c64 fft -> xP -> ifft (f32(1/768) scale) ->
// .real -> f32 score.
// ---------------------------------------------------------------------------
__global__ __launch_bounds__(256) void fft_rows(const float* __restrict__ x,
                                                const c64* __restrict__ Tg,
                                                const float* __restrict__ Pg,
                                                float* __restrict__ scores) {
    __shared__ c64 T[768];
    __shared__ float P[768];
    __shared__ c64 bufA[4][768];
    __shared__ c64 bufB[4][768];
    const int tid = threadIdx.x, r = tid >> 6, lane = tid & 63;
    for (int m = tid; m < 768; m += 256) { T[m] = Tg[m]; P[m] = Pg[m]; }
    const size_t row = (size_t)blockIdx.x * 4 + r;
    const float* xr = x + row * Dd;
    float xv[12];
    c64* A = bufA[r]; c64* B = bufB[r];
#pragma unroll
    for (int q = 0; q < 12; ++q) {
        int m = lane + 64 * q; xv[q] = xr[m]; A[m] = { xv[q], 0.0f };
    }
    __syncthreads();
    pass8x<true, 96, 1>(lane, A, B, T); __syncthreads();
    pass8x<true, 12, 8>(lane, B, A, T); __syncthreads();
    pass4x<true>(lane, A, B, T);        __syncthreads();
    pass3x<true>(lane, B, A);           __syncthreads();
#pragma unroll
    for (int q = 0; q < 12; ++q) {
        int m = lane + 64 * q;
        A[m] = { fmul(A[m].r, P[m]), fmul(A[m].i, P[m]) };
    }
    __syncthreads();
    pass8x<false, 96, 1>(lane, A, B, T); __syncthreads();
    pass8x<false, 12, 8>(lane, B, A, T); __syncthreads();
    pass4x<false>(lane, A, B, T);        __syncthreads();
    pass3x<false>(lane, B, A);           __syncthreads();
    const float fct = (float)(1.0 / 768.0);
    float* sout = scores + row * Dd;
#pragma unroll
    for (int q = 0; q < 12; ++q) {
        int m = lane + 64 * q;
        float f = fmul(A[m].r, fct);
        float den = fmaxf(fabsf(fsub(f, xv[q])), 1e-6f);
        sout[m] = xv[q] / den;
    }
}

// ---------------------------------------------------------------------------
// Kernel B: per-(b,d) top-8 over n (stable: LOWER index first on exact ties,
// = lax.top_k / stable argsort), pooled mean, sel_idx, votes.
// ---------------------------------------------------------------------------
__global__ __launch_bounds__(256) void pass_b(const float* __restrict__ x,
                                              const float* __restrict__ scores,
                                              float* __restrict__ pooled,
                                              float* __restrict__ votes,
                                              float* __restrict__ sel) {
    __shared__ float svals[256][TOPK];
    __shared__ int sids[256][TOPK];

    const int tid = threadIdx.x;
    const int g = tid & 63;
    const int slice = tid >> 6;
    const int b = blockIdx.x / 12;
    const int d = (blockIdx.x % 12) * 64 + g;

    float s[TOPK]; int id[TOPK];
#pragma unroll
    for (int i = 0; i < TOPK; ++i) { s[i] = -INFINITY; id[i] = 0x7fffffff; }

    const float* sp = scores + ((size_t)b * Nn + (size_t)slice * 256) * Dd + d;
    for (int n = 0; n < 256; ++n) {
        float v = sp[(size_t)n * Dd];
        if (v > s[TOPK - 1]) {                   // strict: ties keep earlier
            s[TOPK - 1] = v; id[TOPK - 1] = slice * 256 + n;
#pragma unroll
            for (int p = TOPK - 1; p >= 1; --p) {
                if (s[p] > s[p - 1]) {
                    float ts = s[p]; s[p] = s[p - 1]; s[p - 1] = ts;
                    int ti = id[p]; id[p] = id[p - 1]; id[p - 1] = ti;
                }
            }
        }
    }

#pragma unroll
    for (int i = 0; i < TOPK; ++i) { svals[tid][i] = s[i]; sids[tid][i] = id[i]; }
    __syncthreads();

    if (slice == 0) {
        for (int m = 1; m < 4; ++m) {
            for (int i = 0; i < TOPK; ++i) {
                float v = svals[m * 64 + g][i];
                int vid = sids[m * 64 + g][i];
                if (v > s[TOPK - 1] ||
                    (v == s[TOPK - 1] && vid < id[TOPK - 1])) {
                    s[TOPK - 1] = v; id[TOPK - 1] = vid;
#pragma unroll
                    for (int p = TOPK - 1; p >= 1; --p) {
                        bool sw = (s[p] > s[p - 1]) ||
                                  (s[p] == s[p - 1] && id[p] < id[p - 1]);
                        if (sw) {
                            float ts = s[p]; s[p] = s[p - 1]; s[p - 1] = ts;
                            int ti = id[p]; id[p] = id[p - 1]; id[p - 1] = ti;
                        }
                    }
                }
            }
        }

        float sum = 0.0f;
        const float* xb = x + (size_t)b * Nn * Dd + d;
#pragma unroll
        for (int i = 0; i < TOPK; ++i) {
            sel[((size_t)b * TOPK + i) * Dd + d] = (float)id[i];
            sum += xb[(size_t)id[i] * Dd];
            atomicAdd(&votes[b * Nn + id[i]], 1.0f);
        }
        pooled[(size_t)b * Dd + d] = sum * 0.125f;
    }
}

// ---------------------------------------------------------------------------
extern "C" void kernel_launch(void* const* d_in, const int* in_sizes, int n_in,
                              void* d_out, int out_size, void* d_ws, size_t ws_size,
                              hipStream_t stream) {
    const float* x = (const float*)d_in[0];
    float* out = (float*)d_out;

    float* pooled = out;                          // [64,768]
    float* votes = out + Bsz * Dd;                // [64,1024]
    float* sel = out + Bsz * Dd + Bsz * Nn;       // [64,8,768]

    c64* Tg = (c64*)d_ws;                             // 768 c64
    float* Pg = (float*)((char*)d_ws + 8192);         // 768 f32
    float* scores = (float*)((char*)d_ws + 16384);    // [64,1024,768] f32

    build_tables<<<1, 1024, 0, stream>>>(Tg, Pg);
    zero_votes<<<(Bsz * Nn) / 256, 256, 0, stream>>>(votes);
    fft_rows<<<(Bsz * Nn) / 4, 256, 0, stream>>>(x, Tg, Pg, scores);
    pass_b<<<Bsz * (Dd / 64), 256, 0, stream>>>(x, scores, pooled, votes, sel);
}